// Round 9
// baseline (229.659 us; speedup 1.0000x reference)
//
#include <hip/hip_runtime.h>
#include <hip/hip_bf16.h>
#include <cstdint>

#define D     2048
#define NP    64
#define NC    32
#define T     16384

// d_out float offsets (y, props, satisfaction, consistency, loss)
#define Y_OFF   0
#define P_OFF   33554432
#define S_OFF   34603008
#define C_OFF   35127296
#define L_OFF   35143680

// ws float offsets
#define WS_LPART 0        // [1024]
#define WS_SUMP  1024     // [32] fp32
#define WS_PWF   1056     // bf16 frags [64 kc][4 jt][64 lane][8]
#define WS_EF    66592    // bf16 frags [128 dt][2 kc][64 lane][8]
#define WS_W1F   132128   // bf16 frags [8 nt][4 kc][64][8]
#define WS_W2F   140320   // bf16 frags [4 nt][4 kc][64][8]
#define WS_WMF   144416   // bf16 frags [2 nt][2 kc][64][8]
#define WS_WLF   145440   // bf16 frags [4 nt][64][8]
#define WS_PROPS0 146464  // [16384][64] fp32 props0 staging (k1 -> k3f)
// end 1195040 floats (~4.8 MB)

typedef short short8 __attribute__((ext_vector_type(8)));
typedef float f32x4 __attribute__((ext_vector_type(4)));

__device__ __forceinline__ float sigf(float z) { return 1.0f / (1.0f + __expf(-z)); }
__device__ __forceinline__ short f2bf(float f) {
  unsigned u = __float_as_uint(f);
  return (short)((u + 0x8000u) >> 16);
}
__device__ __forceinline__ unsigned pk2(float a, float b) {
  return ((unsigned)(unsigned short)f2bf(a)) | (((unsigned)(unsigned short)f2bf(b)) << 16);
}

// ---------------- K0: weight pre-transforms + MFMA fragment packing ----------------
__global__ __launch_bounds__(256) void k0_prep(const float* __restrict__ cm, const float* __restrict__ pol,
                                               const float* __restrict__ w1, const float* __restrict__ w2,
                                               const float* __restrict__ pw, const float* __restrict__ ew,
                                               float* __restrict__ ws) {
  int gid = blockIdx.x * 256 + threadIdx.x;
  int stride = gridDim.x * 256;
  short* pwF = (short*)(ws + WS_PWF);
  for (int idx = gid; idx < 64 * 4 * 64; idx += stride) {
    int kc = idx >> 8, jt = (idx >> 6) & 3, l = idx & 63;
    int j = 16 * jt + (l & 15), k = 32 * kc + 8 * (l >> 4);
    const float* src = &pw[(size_t)j * D + k];
    short8 v;
#pragma unroll
    for (int e = 0; e < 8; ++e) v[e] = f2bf(src[e]);
    *(short8*)&pwF[idx * 8] = v;
  }
  short* eF = (short*)(ws + WS_EF);
  for (int idx = gid; idx < 128 * 2 * 64; idx += stride) {
    int dt = idx >> 7, kc = (idx >> 6) & 1, l = idx & 63;
    int d = 16 * dt + (l & 15), j = 32 * kc + 8 * (l >> 4);
    const float* src = &ew[(size_t)d * NP + j];
    short8 v;
#pragma unroll
    for (int e = 0; e < 8; ++e) v[e] = f2bf(src[e]);
    *(short8*)&eF[idx * 8] = v;
  }
  short* w1F = (short*)(ws + WS_W1F);
  for (int idx = gid; idx < 8 * 4 * 64; idx += stride) {
    int nt = idx >> 8, kc = (idx >> 6) & 3, l = idx & 63;
    int m = 16 * nt + (l & 15), k = 32 * kc + 8 * (l >> 4);
    const float* src = &w1[(size_t)m * 128 + k];
    short8 v;
#pragma unroll
    for (int e = 0; e < 8; ++e) v[e] = f2bf(src[e]);
    *(short8*)&w1F[idx * 8] = v;
  }
  short* w2F = (short*)(ws + WS_W2F);
  for (int idx = gid; idx < 4 * 4 * 64; idx += stride) {
    int nt = idx >> 8, kc = (idx >> 6) & 3, l = idx & 63;
    int j = 16 * nt + (l & 15), k = 32 * kc + 8 * (l >> 4);
    const float* src = &w2[(size_t)j * 128 + k];
    short8 v;
#pragma unroll
    for (int e = 0; e < 8; ++e) v[e] = f2bf(src[e]);
    *(short8*)&w2F[idx * 8] = v;
  }
  short* wmF = (short*)(ws + WS_WMF);
  for (int idx = gid; idx < 2 * 2 * 64; idx += stride) {
    int nt = idx >> 7, kc = (idx >> 6) & 1, l = idx & 63;
    int i = 16 * nt + (l & 15), j = 32 * kc + 8 * (l >> 4);
    short8 v;
#pragma unroll
    for (int e = 0; e < 8; ++e)
      v[e] = f2bf(sigf(cm[i * 64 + j + e]) - sigf(pol[i * 64 + j + e]));
    *(short8*)&wmF[idx * 8] = v;
  }
  short* wlF = (short*)(ws + WS_WLF);
  for (int idx = gid; idx < 4 * 64; idx += stride) {
    int nt = idx >> 6, l = idx & 63;
    int j = 16 * nt + (l & 15), i0 = 8 * (l >> 4);
    short8 v;
#pragma unroll
    for (int e = 0; e < 8; ++e) v[e] = f2bf(sigf(cm[(i0 + e) * 64 + j]));
    *(short8*)&wlF[idx * 8] = v;
  }
  if (gid < NC) {
    float s = 0.f;
    for (int j = 0; j < NP; ++j) s += sigf(pol[gid * NP + j]);
    ws[WS_SUMP + gid] = s;
  }
}

// ---------------- K1: props0 = sigmoid(x @ prop_w.T + pb) via MFMA, LDS-staged x ----------------
// grid 1024 (16 tokens/block), 4 waves = 4 j-tiles. x chunk [16t][256k] bf16 in LDS, XOR-swizzled.
// Swapped operands: C = W * x^T -> lane holds (col=token lr, rows j = 16jt+4lg+q) -> float4 stores.
__global__ __launch_bounds__(256) void k1_props(const float* __restrict__ x, const float* __restrict__ ws,
                                                const float* __restrict__ pb, float* __restrict__ props0) {
  __shared__ char XT[8192];  // [16][256] bf16, byte_off ^= (row&7)<<4
  int tid = threadIdx.x, lane = tid & 63;
  int jt = __builtin_amdgcn_readfirstlane(tid >> 6);
  int wv = tid >> 6;
  int t0 = blockIdx.x * 16;
  int lr = lane & 15, lg = lane >> 4;
  int c64 = tid & 63;
  const short* pwF = (const short*)(ws + WS_PWF);

  f32x4 acc = {0.f, 0.f, 0.f, 0.f};
  for (int c = 0; c < 8; ++c) {
    float4 st[4];
#pragma unroll
    for (int j = 0; j < 4; ++j)
      st[j] = *(const float4*)&x[(size_t)(t0 + wv + 4 * j) * D + 256 * c + 4 * c64];
    __syncthreads();  // prior chunk's ds_reads complete before overwrite
#pragma unroll
    for (int j = 0; j < 4; ++j) {
      int tt = wv + 4 * j;
      int off = (tt * 512 + 8 * c64) ^ ((tt & 7) << 4);
      *(uint2*)(XT + off) = make_uint2(pk2(st[j].x, st[j].y), pk2(st[j].z, st[j].w));
    }
    __syncthreads();
#pragma unroll
    for (int kcL = 0; kcL < 8; ++kcL) {
      const short8 b = *(const short8*)(XT + ((lr * 512 + 64 * kcL + 16 * lg) ^ ((lr & 7) << 4)));
      const short8 a = *(const short8*)&pwF[(((8 * c + kcL) * 4 + jt) * 64 + lane) * 8];
      acc = __builtin_amdgcn_mfma_f32_16x16x32_bf16(a, b, acc, 0, 0, 0);
    }
  }
  int j0 = 16 * jt + 4 * lg;
  const float4 pbv = *(const float4*)&pb[j0];
  float4 o;
  o.x = sigf(acc[0] + pbv.x); o.y = sigf(acc[1] + pbv.y);
  o.z = sigf(acc[2] + pbv.z); o.w = sigf(acc[3] + pbv.w);
  *(float4*)&props0[(size_t)(t0 + lr) * 64 + j0] = o;
}

// ---------------- K3f: fused correction (wave 0) + emb GEMM + RMSNorm (all waves) ----------------
// grid 1024 (16 tokens/block), 512 threads = 8 waves.
// Waves 1-7 preload x into regs (HBM stays busy) while wave 0 runs the 3 correction iters
// wave-privately in LDS; final props stay in the LDS H-tile = exact MFMA B-fragment layout.
// One barrier, then all waves: C = emb * props^T, residual, RMSNorm, store.
__global__ __launch_bounds__(512, 4) void k3f(const float* __restrict__ x, const float* __restrict__ ws,
                                              const float* __restrict__ b1, const float* __restrict__ b2,
                                              const float* __restrict__ cw, const float* __restrict__ cb,
                                              const float* __restrict__ eb, const float* __restrict__ nw,
                                              const float* __restrict__ props0,
                                              float* __restrict__ out, float* __restrict__ lpart) {
  __shared__ __align__(16) char Lraw[9216];   // Hb 4K | H2b 4K | SBb 1K
  __shared__ float cons16[16];
  __shared__ float ssp[8][16];
  __shared__ float sc16[16];
  char* Hb = Lraw;
  char* H2b = Lraw + 4096;
  char* SBb = Lraw + 8192;
  int tid = threadIdx.x, lane = tid & 63;
  int wu = __builtin_amdgcn_readfirstlane(tid >> 6);
  int t0 = blockIdx.x * 16;
  int lr = lane & 15, lg = lane >> 4;
  const short* eF = (const short*)(ws + WS_EF);

#define LDSFENCE do { asm volatile("s_waitcnt lgkmcnt(0)" ::: "memory"); \
                      __builtin_amdgcn_sched_barrier(0); } while (0)
#define LDF(base, row, kelem, rowB) \
  (*(const short8*)((base) + ((((row) * (rowB)) + (kelem) * 2) ^ (((row) & 7) << 4))))
#define STBF(base, row, kelem, rowB, val) \
  (*(short*)((base) + ((((row) * (rowB)) + (kelem) * 2) ^ (((row) & 7) << 4))) = f2bf(val))

  if (wu == 0) {
    // ================= correction iterations (single wave, LDS fences only) =================
    const short8* w1F = (const short8*)(ws + WS_W1F);
    const short8* w2F = (const short8*)(ws + WS_W2F);
    const short8* wmF = (const short8*)(ws + WS_WMF);
    const short8* wlF = (const short8*)(ws + WS_WLF);
    const float* SUMP = ws + WS_SUMP;

    float b1v[8], b2v[4], sumpv[2], cwv[2];
#pragma unroll
    for (int nt = 0; nt < 8; ++nt) b1v[nt] = b1[16 * nt + lr];
#pragma unroll
    for (int nt = 0; nt < 4; ++nt) b2v[nt] = b2[16 * nt + lr];
#pragma unroll
    for (int nt = 0; nt < 2; ++nt) { sumpv[nt] = SUMP[16 * nt + lr]; cwv[nt] = cw[16 * nt + lr]; }
    float cb0 = cb[0];

    // init H from props0 (coalesced float4 loads)
#pragma unroll
    for (int r = 0; r < 4; ++r) {
      int idx = r * 64 + lane;
      int t = idx >> 4, c4 = idx & 15;
      const float4 v = *(const float4*)&props0[(size_t)(t0 + t) * 64 + 4 * c4];
      int off = (t * 256 + c4 * 8) ^ ((t & 7) << 4);
      *(unsigned*)(Hb + off) = pk2(v.x, v.y);
      *(unsigned*)(Hb + off + 4) = pk2(v.z, v.w);
    }
    LDSFENCE;

    const f32x4 zf = {0.f, 0.f, 0.f, 0.f};
    f32x4 s0, s1;

    for (int it = 0; it < 3; ++it) {
      short8 ap0 = LDF(Hb, lr, 8 * lg, 256);
      short8 ap1 = LDF(Hb, lr, 32 + 8 * lg, 256);
      s0 = zf; s1 = zf;
      s0 = __builtin_amdgcn_mfma_f32_16x16x32_bf16(ap0, wmF[0 * 64 + lane], s0, 0, 0, 0);
      s0 = __builtin_amdgcn_mfma_f32_16x16x32_bf16(ap1, wmF[1 * 64 + lane], s0, 0, 0, 0);
      s1 = __builtin_amdgcn_mfma_f32_16x16x32_bf16(ap0, wmF[2 * 64 + lane], s1, 0, 0, 0);
      s1 = __builtin_amdgcn_mfma_f32_16x16x32_bf16(ap1, wmF[3 * 64 + lane], s1, 0, 0, 0);
#pragma unroll
      for (int q = 0; q < 4; ++q) {
        int t = 4 * lg + q;
        STBF(SBb, t, lr, 64, 1.f - (s0[q] + sumpv[0]) * (1.f / 64.f));
        STBF(SBb, t, 16 + lr, 64, 1.f - (s1[q] + sumpv[1]) * (1.f / 64.f));
      }
      LDSFENCE;

      short8 as = LDF(SBb, lr, 8 * lg, 64);
      f32x4 vv0 = __builtin_amdgcn_mfma_f32_16x16x32_bf16(as, wlF[0 * 64 + lane], zf, 0, 0, 0);
      f32x4 vv1 = __builtin_amdgcn_mfma_f32_16x16x32_bf16(as, wlF[1 * 64 + lane], zf, 0, 0, 0);
      f32x4 vv2 = __builtin_amdgcn_mfma_f32_16x16x32_bf16(as, wlF[2 * 64 + lane], zf, 0, 0, 0);
      f32x4 vv3 = __builtin_amdgcn_mfma_f32_16x16x32_bf16(as, wlF[3 * 64 + lane], zf, 0, 0, 0);
      const float vs = 1.0f / (32.0f + 1e-6f);
#pragma unroll
      for (int q = 0; q < 4; ++q) {
        int t = 4 * lg + q;
        STBF(Hb, t, 64 + lr, 256, vv0[q] * vs);
        STBF(Hb, t, 64 + 16 + lr, 256, vv1[q] * vs);
        STBF(Hb, t, 64 + 32 + lr, 256, vv2[q] * vs);
        STBF(Hb, t, 64 + 48 + lr, 256, vv3[q] * vs);
      }
      LDSFENCE;

      short8 ah2 = LDF(Hb, lr, 64 + 8 * lg, 256);
      short8 ah3 = LDF(Hb, lr, 96 + 8 * lg, 256);
      f32x4 g1[8];
#pragma unroll
      for (int nt = 0; nt < 8; ++nt) {
        f32x4 a = zf;
        a = __builtin_amdgcn_mfma_f32_16x16x32_bf16(ap0, w1F[(nt * 4 + 0) * 64 + lane], a, 0, 0, 0);
        a = __builtin_amdgcn_mfma_f32_16x16x32_bf16(ap1, w1F[(nt * 4 + 1) * 64 + lane], a, 0, 0, 0);
        a = __builtin_amdgcn_mfma_f32_16x16x32_bf16(ah2, w1F[(nt * 4 + 2) * 64 + lane], a, 0, 0, 0);
        a = __builtin_amdgcn_mfma_f32_16x16x32_bf16(ah3, w1F[(nt * 4 + 3) * 64 + lane], a, 0, 0, 0);
        g1[nt] = a;
      }
#pragma unroll
      for (int nt = 0; nt < 8; ++nt) {
#pragma unroll
        for (int q = 0; q < 4; ++q) {
          float v = g1[nt][q] + b1v[nt];
          float gl = 0.5f * v * (1.0f + erff(v * 0.70710678118654752f));
          STBF(H2b, 4 * lg + q, 16 * nt + lr, 256, gl);
        }
      }
      LDSFENCE;

      short8 ab0 = LDF(H2b, lr, 8 * lg, 256);
      short8 ab1 = LDF(H2b, lr, 32 + 8 * lg, 256);
      short8 ab2 = LDF(H2b, lr, 64 + 8 * lg, 256);
      short8 ab3 = LDF(H2b, lr, 96 + 8 * lg, 256);
#pragma unroll
      for (int nt = 0; nt < 4; ++nt) {
        f32x4 a = zf;
        a = __builtin_amdgcn_mfma_f32_16x16x32_bf16(ab0, w2F[(nt * 4 + 0) * 64 + lane], a, 0, 0, 0);
        a = __builtin_amdgcn_mfma_f32_16x16x32_bf16(ab1, w2F[(nt * 4 + 1) * 64 + lane], a, 0, 0, 0);
        a = __builtin_amdgcn_mfma_f32_16x16x32_bf16(ab2, w2F[(nt * 4 + 2) * 64 + lane], a, 0, 0, 0);
        a = __builtin_amdgcn_mfma_f32_16x16x32_bf16(ab3, w2F[(nt * 4 + 3) * 64 + lane], a, 0, 0, 0);
#pragma unroll
        for (int q = 0; q < 4; ++q) {
          int t = 4 * lg + q;
          float p = sigf(a[q] + b2v[nt]);
          STBF(Hb, t, 16 * nt + lr, 256, p);
          if (it == 2) out[P_OFF + (size_t)(t0 + t) * 64 + 16 * nt + lr] = p;
        }
      }
      LDSFENCE;
    }

    // final satisfaction + consistency + loss partial
    {
      short8 ap0 = LDF(Hb, lr, 8 * lg, 256);
      short8 ap1 = LDF(Hb, lr, 32 + 8 * lg, 256);
      s0 = zf; s1 = zf;
      s0 = __builtin_amdgcn_mfma_f32_16x16x32_bf16(ap0, wmF[0 * 64 + lane], s0, 0, 0, 0);
      s0 = __builtin_amdgcn_mfma_f32_16x16x32_bf16(ap1, wmF[1 * 64 + lane], s0, 0, 0, 0);
      s1 = __builtin_amdgcn_mfma_f32_16x16x32_bf16(ap0, wmF[2 * 64 + lane], s1, 0, 0, 0);
      s1 = __builtin_amdgcn_mfma_f32_16x16x32_bf16(ap1, wmF[3 * 64 + lane], s1, 0, 0, 0);
      float ls = 0.f;
      float csum[4];
#pragma unroll
      for (int q = 0; q < 4; ++q) {
        int t = 4 * lg + q;
        float sa = (s0[q] + sumpv[0]) * (1.f / 64.f);
        float sb = (s1[q] + sumpv[1]) * (1.f / 64.f);
        out[S_OFF + (size_t)(t0 + t) * 32 + lr] = sa;
        out[S_OFF + (size_t)(t0 + t) * 32 + 16 + lr] = sb;
        ls += (1.f - sa) + (1.f - sb);
        csum[q] = cwv[0] * sa + cwv[1] * sb;
      }
#pragma unroll
      for (int m = 1; m <= 8; m <<= 1) {
#pragma unroll
        for (int q = 0; q < 4; ++q) csum[q] += __shfl_xor(csum[q], m);
      }
      if (lr == 0) {
#pragma unroll
        for (int q = 0; q < 4; ++q) {
          float cv = sigf(csum[q] + cb0);
          cons16[4 * lg + q] = cv;
          out[C_OFF + t0 + 4 * lg + q] = cv;
        }
      }
#pragma unroll
      for (int m = 1; m <= 32; m <<= 1) ls += __shfl_xor(ls, m);
      if (lane == 0) lpart[blockIdx.x] = ls;
    }
  }

  // ---- x preload into registers (waves 1-7 issue these while wave 0 computes;
  //      wave 0 issues after correction, hidden across the barrier) ----
  float4 xr[16];
#pragma unroll
  for (int dt2 = 0; dt2 < 16; ++dt2) {
    int d0 = 16 * (wu * 16 + dt2) + 4 * lg;
    xr[dt2] = *(const float4*)&x[(size_t)(t0 + lr) * D + d0];
  }
  __syncthreads();

  // ---- all waves: emb GEMM + residual + RMSNorm ----
  short8 p0 = LDF(Hb, lr, 8 * lg, 256);
  short8 p1 = LDF(Hb, lr, 32 + 8 * lg, 256);
  float consv = cons16[lr];

  uint2 yv[16];  // packed bf16 y — static indexing only (full unroll required)
  float ss = 0.f;
#pragma unroll
  for (int dt2 = 0; dt2 < 16; ++dt2) {
    int dt = wu * 16 + dt2;
    const short8 e0 = *(const short8*)&eF[((dt * 2 + 0) * 64 + lane) * 8];
    const short8 e1 = *(const short8*)&eF[((dt * 2 + 1) * 64 + lane) * 8];
    f32x4 acc = {0.f, 0.f, 0.f, 0.f};
    acc = __builtin_amdgcn_mfma_f32_16x16x32_bf16(e0, p0, acc, 0, 0, 0);
    acc = __builtin_amdgcn_mfma_f32_16x16x32_bf16(e1, p1, acc, 0, 0, 0);
    int d0 = 16 * dt + 4 * lg;
    const float4 ebv = *(const float4*)&eb[d0];
    float y0 = fmaf(acc[0] + ebv.x, consv, xr[dt2].x);
    float y1 = fmaf(acc[1] + ebv.y, consv, xr[dt2].y);
    float y2 = fmaf(acc[2] + ebv.z, consv, xr[dt2].z);
    float y3 = fmaf(acc[3] + ebv.w, consv, xr[dt2].w);
    ss += y0 * y0 + y1 * y1 + y2 * y2 + y3 * y3;
    yv[dt2] = make_uint2(pk2(y0, y1), pk2(y2, y3));
  }
  ss += __shfl_xor(ss, 16);
  ss += __shfl_xor(ss, 32);
  if (lg == 0) ssp[wu][lr] = ss;
  __syncthreads();
  if (tid < 16) {
    float s = 0.f;
#pragma unroll
    for (int w = 0; w < 8; ++w) s += ssp[w][tid];
    sc16[tid] = rsqrtf(s * (1.0f / 2048.0f) + 1e-6f);
  }
  __syncthreads();
  float sc = sc16[lr];
#pragma unroll
  for (int dt2 = 0; dt2 < 16; ++dt2) {
    int d0 = 16 * (wu * 16 + dt2) + 4 * lg;
    const float4 nwv = *(const float4*)&nw[d0];
    uint2 p = yv[dt2];
    float4 o;
    o.x = __uint_as_float(p.x << 16) * sc * nwv.x;
    o.y = __uint_as_float(p.x & 0xffff0000u) * sc * nwv.y;
    o.z = __uint_as_float(p.y << 16) * sc * nwv.z;
    o.w = __uint_as_float(p.y & 0xffff0000u) * sc * nwv.w;
    *(float4*)&out[Y_OFF + (size_t)(t0 + lr) * D + d0] = o;
  }
#undef LDF
#undef STBF
#undef LDSFENCE
}

// ---------------- K4: loss reduce (1024 partials) ----------------
__global__ __launch_bounds__(256) void k4_loss(const float* __restrict__ lpart, float* __restrict__ loss) {
  __shared__ float w[4];
  int tid = threadIdx.x;
  float v = 0.f;
#pragma unroll
  for (int r = 0; r < 4; ++r) v += lpart[tid + 256 * r];
  for (int o = 32; o > 0; o >>= 1) v += __shfl_down(v, o);
  if ((tid & 63) == 0) w[tid >> 6] = v;
  __syncthreads();
  if (tid == 0)
    loss[0] = (w[0] + w[1] + w[2] + w[3]) * (1.0f / (16384.0f * 32.0f));
}

extern "C" void kernel_launch(void* const* d_in, const int* in_sizes, int n_in,
                              void* d_out, int out_size, void* d_ws, size_t ws_size,
                              hipStream_t stream) {
  (void)in_sizes; (void)n_in; (void)out_size; (void)ws_size;
  const float* x   = (const float*)d_in[0];
  const float* pw  = (const float*)d_in[1];
  const float* pb  = (const float*)d_in[2];
  const float* cm  = (const float*)d_in[3];
  const float* pol = (const float*)d_in[4];
  const float* w1  = (const float*)d_in[5];
  const float* b1  = (const float*)d_in[6];
  const float* w2  = (const float*)d_in[7];
  const float* b2  = (const float*)d_in[8];
  const float* cw  = (const float*)d_in[9];
  const float* cb  = (const float*)d_in[10];
  const float* ew  = (const float*)d_in[11];
  const float* eb  = (const float*)d_in[12];
  const float* nw  = (const float*)d_in[13];
  float* out = (float*)d_out;
  float* ws  = (float*)d_ws;

  hipLaunchKernelGGL(k0_prep, dim3(128), dim3(256), 0, stream, cm, pol, w1, w2, pw, ew, ws);
  hipLaunchKernelGGL(k1_props, dim3(1024), dim3(256), 0, stream, x, ws, pb, ws + WS_PROPS0);
  hipLaunchKernelGGL(k3f, dim3(1024), dim3(512), 0, stream, x, ws, b1, b2, cw, cb, eb, nw,
                     ws + WS_PROPS0, out, ws + WS_LPART);
  hipLaunchKernelGGL(k4_loss, dim3(1), dim3(256), 0, stream, ws + WS_LPART, out + L_OFF);
}

// Round 10
// 124.710 us; speedup vs baseline: 1.8415x; 1.8415x over previous
//
#include <hip/hip_runtime.h>
#include <hip/hip_bf16.h>
#include <cstdint>

#define D     2048
#define NP    64
#define NC    32
#define T     16384

// d_out float offsets (y, props, satisfaction, consistency, loss)
#define Y_OFF   0
#define P_OFF   33554432
#define S_OFF   34603008
#define C_OFF   35127296
#define L_OFF   35143680

// ws float offsets
#define WS_LPART 0        // [1024]
#define WS_SUMP  1024     // [32] fp32
#define WS_PWF   1056     // bf16 frags [64 kc][4 jt][64 lane][8]
#define WS_EF    66592    // bf16 frags [128 dt][2 kc][64 lane][8]
#define WS_W1F   132128   // bf16 frags [8 nt][4 kc][64][8]
#define WS_W2F   140320   // bf16 frags [4 nt][4 kc][64][8]
#define WS_WMF   144416   // bf16 frags [2 nt][2 kc][64][8]
#define WS_WLF   145440   // bf16 frags [4 nt][64][8]
// end 146464 floats (~586 KB)

typedef short short8 __attribute__((ext_vector_type(8)));
typedef float f32x4 __attribute__((ext_vector_type(4)));

__device__ __forceinline__ float sigf(float z) { return 1.0f / (1.0f + __expf(-z)); }
__device__ __forceinline__ short f2bf(float f) {
  unsigned u = __float_as_uint(f);
  return (short)((u + 0x8000u) >> 16);
}
__device__ __forceinline__ unsigned pk2(float a, float b) {
  return ((unsigned)(unsigned short)f2bf(a)) | (((unsigned)(unsigned short)f2bf(b)) << 16);
}

// ---------------- K0: weight pre-transforms + MFMA fragment packing ----------------
__global__ __launch_bounds__(256) void k0_prep(const float* __restrict__ cm, const float* __restrict__ pol,
                                               const float* __restrict__ w1, const float* __restrict__ w2,
                                               const float* __restrict__ pw, const float* __restrict__ ew,
                                               float* __restrict__ ws) {
  int gid = blockIdx.x * 256 + threadIdx.x;
  int stride = gridDim.x * 256;
  short* pwF = (short*)(ws + WS_PWF);
  for (int idx = gid; idx < 64 * 4 * 64; idx += stride) {
    int kc = idx >> 8, jt = (idx >> 6) & 3, l = idx & 63;
    int j = 16 * jt + (l & 15), k = 32 * kc + 8 * (l >> 4);
    const float* src = &pw[(size_t)j * D + k];
    short8 v;
#pragma unroll
    for (int e = 0; e < 8; ++e) v[e] = f2bf(src[e]);
    *(short8*)&pwF[idx * 8] = v;
  }
  short* eF = (short*)(ws + WS_EF);
  for (int idx = gid; idx < 128 * 2 * 64; idx += stride) {
    int dt = idx >> 7, kc = (idx >> 6) & 1, l = idx & 63;
    int d = 16 * dt + (l & 15), j = 32 * kc + 8 * (l >> 4);
    const float* src = &ew[(size_t)d * NP + j];
    short8 v;
#pragma unroll
    for (int e = 0; e < 8; ++e) v[e] = f2bf(src[e]);
    *(short8*)&eF[idx * 8] = v;
  }
  short* w1F = (short*)(ws + WS_W1F);
  for (int idx = gid; idx < 8 * 4 * 64; idx += stride) {
    int nt = idx >> 8, kc = (idx >> 6) & 3, l = idx & 63;
    int m = 16 * nt + (l & 15), k = 32 * kc + 8 * (l >> 4);
    const float* src = &w1[(size_t)m * 128 + k];
    short8 v;
#pragma unroll
    for (int e = 0; e < 8; ++e) v[e] = f2bf(src[e]);
    *(short8*)&w1F[idx * 8] = v;
  }
  short* w2F = (short*)(ws + WS_W2F);
  for (int idx = gid; idx < 4 * 4 * 64; idx += stride) {
    int nt = idx >> 8, kc = (idx >> 6) & 3, l = idx & 63;
    int j = 16 * nt + (l & 15), k = 32 * kc + 8 * (l >> 4);
    const float* src = &w2[(size_t)j * 128 + k];
    short8 v;
#pragma unroll
    for (int e = 0; e < 8; ++e) v[e] = f2bf(src[e]);
    *(short8*)&w2F[idx * 8] = v;
  }
  short* wmF = (short*)(ws + WS_WMF);
  for (int idx = gid; idx < 2 * 2 * 64; idx += stride) {
    int nt = idx >> 7, kc = (idx >> 6) & 1, l = idx & 63;
    int i = 16 * nt + (l & 15), j = 32 * kc + 8 * (l >> 4);
    short8 v;
#pragma unroll
    for (int e = 0; e < 8; ++e)
      v[e] = f2bf(sigf(cm[i * 64 + j + e]) - sigf(pol[i * 64 + j + e]));
    *(short8*)&wmF[idx * 8] = v;
  }
  short* wlF = (short*)(ws + WS_WLF);
  for (int idx = gid; idx < 4 * 64; idx += stride) {
    int nt = idx >> 6, l = idx & 63;
    int j = 16 * nt + (l & 15), i0 = 8 * (l >> 4);
    short8 v;
#pragma unroll
    for (int e = 0; e < 8; ++e) v[e] = f2bf(sigf(cm[(i0 + e) * 64 + j]));
    *(short8*)&wlF[idx * 8] = v;
  }
  if (gid < NC) {
    float s = 0.f;
    for (int j = 0; j < NP; ++j) s += sigf(pol[gid * NP + j]);
    ws[WS_SUMP + gid] = s;
  }
}

// ---------------- K1: props0 = sigmoid(x @ prop_w.T + pb) via MFMA, double-buffered LDS x ----
// grid 1024 (16 tokens/block), 4 waves = 4 j-tiles. x chunk [16t][256k] bf16, XOR-swizzled,
// two LDS buffers: prefetch chunk c+1 to regs before the single barrier, write after MFMA.
__global__ __launch_bounds__(256) void k1_props(const float* __restrict__ x, const float* __restrict__ ws,
                                                const float* __restrict__ pb, float* __restrict__ props0) {
  __shared__ char XT[16384];  // 2 x [16][256] bf16, byte_off ^= (row&7)<<4
  int tid = threadIdx.x, lane = tid & 63;
  int jt = __builtin_amdgcn_readfirstlane(tid >> 6);
  int wv = tid >> 6;
  int t0 = blockIdx.x * 16;
  int lr = lane & 15, lg = lane >> 4;
  int c64 = tid & 63;
  const short* pwF = (const short*)(ws + WS_PWF);

  f32x4 acc = {0.f, 0.f, 0.f, 0.f};
  float4 st[4];
  // prologue: load + write chunk 0 into buf0 (no barrier needed yet)
#pragma unroll
  for (int j = 0; j < 4; ++j)
    st[j] = *(const float4*)&x[(size_t)(t0 + wv + 4 * j) * D + 4 * c64];
#pragma unroll
  for (int j = 0; j < 4; ++j) {
    int tt = wv + 4 * j;
    int off = (tt * 512 + 8 * c64) ^ ((tt & 7) << 4);
    *(uint2*)(XT + off) = make_uint2(pk2(st[j].x, st[j].y), pk2(st[j].z, st[j].w));
  }
  for (int c = 0; c < 8; ++c) {
    if (c < 7) {  // prefetch next chunk into regs (in flight across the barrier)
#pragma unroll
      for (int j = 0; j < 4; ++j)
        st[j] = *(const float4*)&x[(size_t)(t0 + wv + 4 * j) * D + 256 * (c + 1) + 4 * c64];
    }
    __syncthreads();  // buf[c&1] writes visible; all reads of buf[(c+1)&1] (iter c-1) drained
    const char* XTr = XT + (c & 1) * 8192;
#pragma unroll
    for (int kcL = 0; kcL < 8; ++kcL) {
      const short8 b = *(const short8*)(XTr + ((lr * 512 + 64 * kcL + 16 * lg) ^ ((lr & 7) << 4)));
      const short8 a = *(const short8*)&pwF[(((8 * c + kcL) * 4 + jt) * 64 + lane) * 8];
      acc = __builtin_amdgcn_mfma_f32_16x16x32_bf16(a, b, acc, 0, 0, 0);
    }
    if (c < 7) {
      char* XTn = XT + ((c + 1) & 1) * 8192;
#pragma unroll
      for (int j = 0; j < 4; ++j) {
        int tt = wv + 4 * j;
        int off = (tt * 512 + 8 * c64) ^ ((tt & 7) << 4);
        *(uint2*)(XTn + off) = make_uint2(pk2(st[j].x, st[j].y), pk2(st[j].z, st[j].w));
      }
    }
  }
  int j0 = 16 * jt + 4 * lg;
  const float4 pbv = *(const float4*)&pb[j0];
  float4 o;
  o.x = sigf(acc[0] + pbv.x); o.y = sigf(acc[1] + pbv.y);
  o.z = sigf(acc[2] + pbv.z); o.w = sigf(acc[3] + pbv.w);
  *(float4*)&props0[(size_t)(t0 + lr) * 64 + j0] = o;
}

// ---------------- K2: correction iterations via MFMA; 1 wave = 16 tokens, wave-private ----------------
// Standalone (high block-level TLP). LDS: H[16][128]bf16 | H2 | SB, XOR-swizzled.
__global__ __launch_bounds__(64) void k2_iter(const float* __restrict__ ws,
                                              const float* __restrict__ b1, const float* __restrict__ b2,
                                              const float* __restrict__ cw, const float* __restrict__ cb,
                                              const float* __restrict__ props0, float* __restrict__ out,
                                              float* __restrict__ lpart) {
  __shared__ char Lraw[9216];
  char* Hb = Lraw;
  char* H2b = Lraw + 4096;
  char* SBb = Lraw + 8192;
  int lane = threadIdx.x & 63;
  int lr = lane & 15, lg = lane >> 4;
  int t0 = blockIdx.x * 16;
  const short8* w1F = (const short8*)(ws + WS_W1F);
  const short8* w2F = (const short8*)(ws + WS_W2F);
  const short8* wmF = (const short8*)(ws + WS_WMF);
  const short8* wlF = (const short8*)(ws + WS_WLF);
  const float* SUMP = ws + WS_SUMP;

  float b1v[8], b2v[4], sumpv[2], cwv[2];
#pragma unroll
  for (int nt = 0; nt < 8; ++nt) b1v[nt] = b1[16 * nt + lr];
#pragma unroll
  for (int nt = 0; nt < 4; ++nt) b2v[nt] = b2[16 * nt + lr];
#pragma unroll
  for (int nt = 0; nt < 2; ++nt) { sumpv[nt] = SUMP[16 * nt + lr]; cwv[nt] = cw[16 * nt + lr]; }
  float cb0 = cb[0];

#pragma unroll
  for (int r = 0; r < 4; ++r) {
    int idx = r * 64 + lane;
    int t = idx >> 4, c4 = idx & 15;
    const float4 v = *(const float4*)&props0[(size_t)(t0 + t) * 64 + 4 * c4];
    int off = (t * 256 + c4 * 8) ^ ((t & 7) << 4);
    *(unsigned*)(Hb + off) = pk2(v.x, v.y);
    *(unsigned*)(Hb + off + 4) = pk2(v.z, v.w);
  }
  __syncthreads();

  const f32x4 zf = {0.f, 0.f, 0.f, 0.f};
  f32x4 s0, s1;

#define LDF(base, row, kelem, rowB) \
  (*(const short8*)((base) + ((((row) * (rowB)) + (kelem) * 2) ^ (((row) & 7) << 4))))
#define STBF(base, row, kelem, rowB, val) \
  (*(short*)((base) + ((((row) * (rowB)) + (kelem) * 2) ^ (((row) & 7) << 4))) = f2bf(val))

  for (int it = 0; it < 3; ++it) {
    short8 ap0 = LDF(Hb, lr, 8 * lg, 256);
    short8 ap1 = LDF(Hb, lr, 32 + 8 * lg, 256);
    s0 = zf; s1 = zf;
    s0 = __builtin_amdgcn_mfma_f32_16x16x32_bf16(ap0, wmF[0 * 64 + lane], s0, 0, 0, 0);
    s0 = __builtin_amdgcn_mfma_f32_16x16x32_bf16(ap1, wmF[1 * 64 + lane], s0, 0, 0, 0);
    s1 = __builtin_amdgcn_mfma_f32_16x16x32_bf16(ap0, wmF[2 * 64 + lane], s1, 0, 0, 0);
    s1 = __builtin_amdgcn_mfma_f32_16x16x32_bf16(ap1, wmF[3 * 64 + lane], s1, 0, 0, 0);
#pragma unroll
    for (int q = 0; q < 4; ++q) {
      int t = 4 * lg + q;
      STBF(SBb, t, lr, 64, 1.f - (s0[q] + sumpv[0]) * (1.f / 64.f));
      STBF(SBb, t, 16 + lr, 64, 1.f - (s1[q] + sumpv[1]) * (1.f / 64.f));
    }
    __syncthreads();

    short8 as = LDF(SBb, lr, 8 * lg, 64);
    f32x4 vv0 = __builtin_amdgcn_mfma_f32_16x16x32_bf16(as, wlF[0 * 64 + lane], zf, 0, 0, 0);
    f32x4 vv1 = __builtin_amdgcn_mfma_f32_16x16x32_bf16(as, wlF[1 * 64 + lane], zf, 0, 0, 0);
    f32x4 vv2 = __builtin_amdgcn_mfma_f32_16x16x32_bf16(as, wlF[2 * 64 + lane], zf, 0, 0, 0);
    f32x4 vv3 = __builtin_amdgcn_mfma_f32_16x16x32_bf16(as, wlF[3 * 64 + lane], zf, 0, 0, 0);
    const float vs = 1.0f / (32.0f + 1e-6f);
#pragma unroll
    for (int q = 0; q < 4; ++q) {
      int t = 4 * lg + q;
      STBF(Hb, t, 64 + lr, 256, vv0[q] * vs);
      STBF(Hb, t, 64 + 16 + lr, 256, vv1[q] * vs);
      STBF(Hb, t, 64 + 32 + lr, 256, vv2[q] * vs);
      STBF(Hb, t, 64 + 48 + lr, 256, vv3[q] * vs);
    }
    __syncthreads();

    short8 ah2 = LDF(Hb, lr, 64 + 8 * lg, 256);
    short8 ah3 = LDF(Hb, lr, 96 + 8 * lg, 256);
    f32x4 g1[8];
#pragma unroll
    for (int nt = 0; nt < 8; ++nt) {
      f32x4 a = zf;
      a = __builtin_amdgcn_mfma_f32_16x16x32_bf16(ap0, w1F[(nt * 4 + 0) * 64 + lane], a, 0, 0, 0);
      a = __builtin_amdgcn_mfma_f32_16x16x32_bf16(ap1, w1F[(nt * 4 + 1) * 64 + lane], a, 0, 0, 0);
      a = __builtin_amdgcn_mfma_f32_16x16x32_bf16(ah2, w1F[(nt * 4 + 2) * 64 + lane], a, 0, 0, 0);
      a = __builtin_amdgcn_mfma_f32_16x16x32_bf16(ah3, w1F[(nt * 4 + 3) * 64 + lane], a, 0, 0, 0);
      g1[nt] = a;
    }
#pragma unroll
    for (int nt = 0; nt < 8; ++nt) {
#pragma unroll
      for (int q = 0; q < 4; ++q) {
        float v = g1[nt][q] + b1v[nt];
        float gl = 0.5f * v * (1.0f + erff(v * 0.70710678118654752f));
        STBF(H2b, 4 * lg + q, 16 * nt + lr, 256, gl);
      }
    }
    __syncthreads();

    short8 ab0 = LDF(H2b, lr, 8 * lg, 256);
    short8 ab1 = LDF(H2b, lr, 32 + 8 * lg, 256);
    short8 ab2 = LDF(H2b, lr, 64 + 8 * lg, 256);
    short8 ab3 = LDF(H2b, lr, 96 + 8 * lg, 256);
#pragma unroll
    for (int nt = 0; nt < 4; ++nt) {
      f32x4 a = zf;
      a = __builtin_amdgcn_mfma_f32_16x16x32_bf16(ab0, w2F[(nt * 4 + 0) * 64 + lane], a, 0, 0, 0);
      a = __builtin_amdgcn_mfma_f32_16x16x32_bf16(ab1, w2F[(nt * 4 + 1) * 64 + lane], a, 0, 0, 0);
      a = __builtin_amdgcn_mfma_f32_16x16x32_bf16(ab2, w2F[(nt * 4 + 2) * 64 + lane], a, 0, 0, 0);
      a = __builtin_amdgcn_mfma_f32_16x16x32_bf16(ab3, w2F[(nt * 4 + 3) * 64 + lane], a, 0, 0, 0);
#pragma unroll
      for (int q = 0; q < 4; ++q) {
        int t = 4 * lg + q;
        float p = sigf(a[q] + b2v[nt]);
        STBF(Hb, t, 16 * nt + lr, 256, p);
        if (it == 2) out[P_OFF + (size_t)(t0 + t) * 64 + 16 * nt + lr] = p;
      }
    }
    __syncthreads();
  }

  {
    short8 ap0 = LDF(Hb, lr, 8 * lg, 256);
    short8 ap1 = LDF(Hb, lr, 32 + 8 * lg, 256);
    s0 = zf; s1 = zf;
    s0 = __builtin_amdgcn_mfma_f32_16x16x32_bf16(ap0, wmF[0 * 64 + lane], s0, 0, 0, 0);
    s0 = __builtin_amdgcn_mfma_f32_16x16x32_bf16(ap1, wmF[1 * 64 + lane], s0, 0, 0, 0);
    s1 = __builtin_amdgcn_mfma_f32_16x16x32_bf16(ap0, wmF[2 * 64 + lane], s1, 0, 0, 0);
    s1 = __builtin_amdgcn_mfma_f32_16x16x32_bf16(ap1, wmF[3 * 64 + lane], s1, 0, 0, 0);
    float ls = 0.f;
    float csum[4];
#pragma unroll
    for (int q = 0; q < 4; ++q) {
      int t = 4 * lg + q;
      float sa = (s0[q] + sumpv[0]) * (1.f / 64.f);
      float sb = (s1[q] + sumpv[1]) * (1.f / 64.f);
      out[S_OFF + (size_t)(t0 + t) * 32 + lr] = sa;
      out[S_OFF + (size_t)(t0 + t) * 32 + 16 + lr] = sb;
      ls += (1.f - sa) + (1.f - sb);
      csum[q] = cwv[0] * sa + cwv[1] * sb;
    }
#pragma unroll
    for (int m = 1; m <= 8; m <<= 1) {
#pragma unroll
      for (int q = 0; q < 4; ++q) csum[q] += __shfl_xor(csum[q], m);
    }
    if (lr == 0) {
#pragma unroll
      for (int q = 0; q < 4; ++q)
        out[C_OFF + t0 + 4 * lg + q] = sigf(csum[q] + cb0);
    }
#pragma unroll
    for (int m = 1; m <= 32; m <<= 1) ls += __shfl_xor(ls, m);
    if (lane == 0) lpart[blockIdx.x] = ls;
  }
#undef LDF
#undef STBF
}

// ---------------- K3n: y = rmsnorm(x + (props@emb_w.T + eb)*cons) * nw, fused (+loss tail) ----
// grid 1024 (16 tokens/block), 512 threads = 8 waves x 256 d. Swapped MFMA: C = emb * props^T
// -> lane holds (col=token lr, rows d = 16dt+4lg+q) -> float4 x/y access. y packed bf16 in regs.
// NOTE: dt2 loops MUST be fully unrolled (yv[dt2] static indexing; partial unroll -> scratch).
__global__ __launch_bounds__(512, 4) void k3n(const float* __restrict__ x, const float* __restrict__ ws,
                                              const float* __restrict__ eb, const float* __restrict__ nw,
                                              const float* __restrict__ lpart, float* __restrict__ out) {
  __shared__ float ssp[8][16];
  __shared__ float sc16[16];
  int tid = threadIdx.x, lane = tid & 63;
  int wu = __builtin_amdgcn_readfirstlane(tid >> 6);
  int t0 = blockIdx.x * 16;
  int lr = lane & 15, lg = lane >> 4;
  const short* eF = (const short*)(ws + WS_EF);

  // loss reduce folded in (block 0, wave 7), overlapped with other blocks' work
  if (blockIdx.x == 0 && wu == 7) {
    float v = 0.f;
#pragma unroll
    for (int r = 0; r < 16; ++r) v += lpart[lane + 64 * r];
#pragma unroll
    for (int m = 1; m <= 32; m <<= 1) v += __shfl_xor(v, m);
    if (lane == 0) out[L_OFF] = v * (1.0f / (16384.0f * 32.0f));
  }

  const float* pr = out + P_OFF + (size_t)(t0 + lr) * 64 + 8 * lg;
  const float4 q0 = *(const float4*)pr;
  const float4 q1 = *(const float4*)(pr + 4);
  const float4 q2 = *(const float4*)(pr + 32);
  const float4 q3 = *(const float4*)(pr + 36);
  short8 p0, p1;
  p0[0] = f2bf(q0.x); p0[1] = f2bf(q0.y); p0[2] = f2bf(q0.z); p0[3] = f2bf(q0.w);
  p0[4] = f2bf(q1.x); p0[5] = f2bf(q1.y); p0[6] = f2bf(q1.z); p0[7] = f2bf(q1.w);
  p1[0] = f2bf(q2.x); p1[1] = f2bf(q2.y); p1[2] = f2bf(q2.z); p1[3] = f2bf(q2.w);
  p1[4] = f2bf(q3.x); p1[5] = f2bf(q3.y); p1[6] = f2bf(q3.z); p1[7] = f2bf(q3.w);

  float consv = out[C_OFF + t0 + lr];

  uint2 yv[16];  // packed bf16 y (4 values per entry) — static indexing only
  float ss = 0.f;
#pragma unroll
  for (int dt2 = 0; dt2 < 16; ++dt2) {
    int dt = wu * 16 + dt2;
    const short8 e0 = *(const short8*)&eF[((dt * 2 + 0) * 64 + lane) * 8];
    const short8 e1 = *(const short8*)&eF[((dt * 2 + 1) * 64 + lane) * 8];
    f32x4 acc = {0.f, 0.f, 0.f, 0.f};
    acc = __builtin_amdgcn_mfma_f32_16x16x32_bf16(e0, p0, acc, 0, 0, 0);
    acc = __builtin_amdgcn_mfma_f32_16x16x32_bf16(e1, p1, acc, 0, 0, 0);
    int d0 = 16 * dt + 4 * lg;
    const float4 ebv = *(const float4*)&eb[d0];
    const float4 xv = *(const float4*)&x[(size_t)(t0 + lr) * D + d0];
    float y0 = fmaf(acc[0] + ebv.x, consv, xv.x);
    float y1 = fmaf(acc[1] + ebv.y, consv, xv.y);
    float y2 = fmaf(acc[2] + ebv.z, consv, xv.z);
    float y3 = fmaf(acc[3] + ebv.w, consv, xv.w);
    ss += y0 * y0 + y1 * y1 + y2 * y2 + y3 * y3;
    yv[dt2] = make_uint2(pk2(y0, y1), pk2(y2, y3));
  }
  ss += __shfl_xor(ss, 16);
  ss += __shfl_xor(ss, 32);
  if (lg == 0) ssp[wu][lr] = ss;
  __syncthreads();
  if (tid < 16) {
    float s = 0.f;
#pragma unroll
    for (int w = 0; w < 8; ++w) s += ssp[w][tid];
    sc16[tid] = rsqrtf(s * (1.0f / 2048.0f) + 1e-6f);
  }
  __syncthreads();
  float sc = sc16[lr];
#pragma unroll
  for (int dt2 = 0; dt2 < 16; ++dt2) {
    int d0 = 16 * (wu * 16 + dt2) + 4 * lg;
    const float4 nwv = *(const float4*)&nw[d0];
    uint2 p = yv[dt2];
    float4 o;
    o.x = __uint_as_float(p.x << 16) * sc * nwv.x;
    o.y = __uint_as_float(p.x & 0xffff0000u) * sc * nwv.y;
    o.z = __uint_as_float(p.y << 16) * sc * nwv.z;
    o.w = __uint_as_float(p.y & 0xffff0000u) * sc * nwv.w;
    *(float4*)&out[Y_OFF + (size_t)(t0 + lr) * D + d0] = o;
  }
}

extern "C" void kernel_launch(void* const* d_in, const int* in_sizes, int n_in,
                              void* d_out, int out_size, void* d_ws, size_t ws_size,
                              hipStream_t stream) {
  (void)in_sizes; (void)n_in; (void)out_size; (void)ws_size;
  const float* x   = (const float*)d_in[0];
  const float* pw  = (const float*)d_in[1];
  const float* pb  = (const float*)d_in[2];
  const float* cm  = (const float*)d_in[3];
  const float* pol = (const float*)d_in[4];
  const float* w1  = (const float*)d_in[5];
  const float* b1  = (const float*)d_in[6];
  const float* w2  = (const float*)d_in[7];
  const float* b2  = (const float*)d_in[8];
  const float* cw  = (const float*)d_in[9];
  const float* cb  = (const float*)d_in[10];
  const float* ew  = (const float*)d_in[11];
  const float* eb  = (const float*)d_in[12];
  const float* nw  = (const float*)d_in[13];
  float* out = (float*)d_out;
  float* ws  = (float*)d_ws;

  hipLaunchKernelGGL(k0_prep, dim3(128), dim3(256), 0, stream, cm, pol, w1, w2, pw, ew, ws);
  // k1 writes sigmoided props0 into the y region of d_out (dead until k3n overwrites it)
  hipLaunchKernelGGL(k1_props, dim3(1024), dim3(256), 0, stream, x, ws, pb, out + Y_OFF);
  hipLaunchKernelGGL(k2_iter, dim3(1024), dim3(64), 0, stream, ws, b1, b2, cw, cb,
                     out + Y_OFF, out, ws + WS_LPART);
  hipLaunchKernelGGL(k3n, dim3(1024), dim3(512), 0, stream, x, ws, eb, nw,
                     ws + WS_LPART, out);
}